// Round 12
// baseline (45.070 us; speedup 1.0000x reference)
//
#include <hip/hip_runtime.h>

#define N_NODES 40000
#define C_DIM   128
#define K_NBR   16

static constexpr float BETA_F  = 0.11778303565638346f;  // log(1.125)
static constexpr float C1_F    = 0.7939952679092549f;   // (1-ALPHA)*(1-BETA)
static constexpr float C2_F    = 0.08822169643436166f;  // ALPHA*(1-BETA)
static constexpr float INV_DEG = 1.0f / 17.0f;

typedef __attribute__((ext_vector_type(8))) short bf16x8;
typedef __attribute__((ext_vector_type(4))) float f32x4;

__device__ __forceinline__ unsigned pack_bf16x2(float a, float b) {
    unsigned ua = __float_as_uint(a), ub = __float_as_uint(b);
    ua += 0x7fffu + ((ua >> 16) & 1u);     // RNE
    ub += 0x7fffu + ((ub >> 16) & 1u);
    return (ua >> 16) | (ub & 0xffff0000u);
}
__device__ __forceinline__ float bflo(unsigned u) { return __uint_as_float(u << 16); }
__device__ __forceinline__ float bfhi(unsigned u) { return __uint_as_float(u & 0xffff0000u); }

// ---------------------------------------------------------------------------
// Kernel 1 (prep) — identical to R7/R11 (best-known): grid = 128 + 1250.
//   blocks 0..127    : folded-W fragment build (parallel, 1 elem/thread).
//   blocks 128..1377 : transpose+cast 32n x 128c of x -> xTb [N][64] u32.
// W'[c][o] = c<128 ? (BETA*W1[o][c] + (c==o)*C1) * INV_DEG
//                  : BETA*W2[o][c-128] + (c-128==o)*C2
// ---------------------------------------------------------------------------
__global__ __launch_bounds__(256) void prep_kernel(
        const float* __restrict__ x,
        const float* __restrict__ W1,
        const float* __restrict__ W2,
        unsigned* __restrict__ xTb,
        unsigned short* __restrict__ WB) {
    __shared__ unsigned lds[32 * 65];   // [n][c2], stride 65 u32 (8320 B)

    const int b = blockIdx.x;
    const int tid = threadIdx.x;

    if (b < 128) {
        const int i = b * 256 + tid;                   // 0 .. 32767
        const int frag = i >> 9, within = i & 511;
        const int lane = within >> 3, j = within & 7;
        const int otile = frag >> 3, kblk = frag & 7;
        const int o = otile * 16 + (lane & 15);
        const int c = kblk * 32 + ((lane >> 4) << 3) + j;
        float v;
        if (c < 128) {
            v = (BETA_F * W1[o * 128 + c] + (c == o ? C1_F : 0.0f)) * INV_DEG;
        } else {
            const int c2 = c - 128;
            v = BETA_F * W2[o * 128 + c2] + (c2 == o ? C2_F : 0.0f);
        }
        unsigned u = __float_as_uint(v);
        u += 0x7fffu + ((u >> 16) & 1u);
        WB[i] = (unsigned short)(u >> 16);
        return;
    }

    const int nb = (b - 128) * 32;

    const int c2 = tid >> 2;          // 0..63
    const int h  = tid & 3;           // n-offset h*8
    const float* r0 = &x[(size_t)(2 * c2)     * N_NODES + nb + h * 8];
    const float* r1 = &x[(size_t)(2 * c2 + 1) * N_NODES + nb + h * 8];
    const float4 a0 = *(const float4*)(r0);
    const float4 a1 = *(const float4*)(r0 + 4);
    const float4 b0 = *(const float4*)(r1);
    const float4 b1 = *(const float4*)(r1 + 4);

    unsigned* lrow = &lds[h * 8 * 65 + c2];
    lrow[0 * 65] = pack_bf16x2(a0.x, b0.x);
    lrow[1 * 65] = pack_bf16x2(a0.y, b0.y);
    lrow[2 * 65] = pack_bf16x2(a0.z, b0.z);
    lrow[3 * 65] = pack_bf16x2(a0.w, b0.w);
    lrow[4 * 65] = pack_bf16x2(a1.x, b1.x);
    lrow[5 * 65] = pack_bf16x2(a1.y, b1.y);
    lrow[6 * 65] = pack_bf16x2(a1.z, b1.z);
    lrow[7 * 65] = pack_bf16x2(a1.w, b1.w);
    __syncthreads();

    const int n = tid >> 3, q = tid & 7;
    const unsigned* src = &lds[n * 65 + q * 8];
    unsigned* dst = &xTb[(size_t)(nb + n) * 64 + q * 8];
    *(uint4*)&dst[0] = make_uint4(src[0], src[1], src[2], src[3]);
    *(uint4*)&dst[4] = make_uint4(src[4], src[5], src[6], src[7]);
}

// ---------------------------------------------------------------------------
// Kernel 2 (fused): gather-sum with FULL 128-B LINE transactions
// (16 lanes per node, 2 half-row passes) + MFMA GEMM + relu/bias epilogue.
// Block = 256 threads (4 waves), 32 nodes/block, grid = 1250.
// ---------------------------------------------------------------------------
__global__ __launch_bounds__(256) void fused5_kernel(
        const unsigned* __restrict__ xTb,     // [N][64] u32 = bf16x2
        const float*    __restrict__ x0,      // [N][128] f32
        const int*      __restrict__ e0,      // [N][16]
        const bf16x8*   __restrict__ WB,      // 64 frags x 64 lanes x 16B
        const float*    __restrict__ bias,    // [128]
        float*          __restrict__ out) {   // [128][N]
    __shared__ unsigned y[32][132];           // [node][sum(64) | x0(64) | pad 4]
    __shared__ int eis[512];

    const int nb   = blockIdx.x * 32;
    const int tid  = threadIdx.x;
    const int lane = tid & 63;
    const int wid  = tid >> 6;

    eis[tid]       = e0[(size_t)nb * K_NBR + tid];
    eis[256 + tid] = e0[(size_t)nb * K_NBR + 256 + tid];
    __syncthreads();

    // ---- Phase 1a: stage x0 tile (bf16) — issued early, independent ----
    {
        const int node = tid >> 3;    // 0..31
        const int g8   = tid & 7;     // 0..7
        const float* r = &x0[(size_t)(nb + node) * C_DIM + g8 * 16];
        const float4 v0 = *(const float4*)(r);
        const float4 v1 = *(const float4*)(r + 4);
        const float4 v2 = *(const float4*)(r + 8);
        const float4 v3 = *(const float4*)(r + 12);
        uint4 ua, ub;
        ua.x = pack_bf16x2(v0.x, v0.y);  ua.y = pack_bf16x2(v0.z, v0.w);
        ua.z = pack_bf16x2(v1.x, v1.y);  ua.w = pack_bf16x2(v1.z, v1.w);
        ub.x = pack_bf16x2(v2.x, v2.y);  ub.y = pack_bf16x2(v2.z, v2.w);
        ub.z = pack_bf16x2(v3.x, v3.y);  ub.w = pack_bf16x2(v3.z, v3.w);
        *(uint4*)&y[node][64 + g8 * 8]     = ua;
        *(uint4*)&y[node][64 + g8 * 8 + 4] = ub;
    }

    // ---- Phase 1b: gather-sum; each (node,k) read = one 128-B line ----
    const int ng  = tid >> 4;         // 0..15
    const int l16 = tid & 15;
#pragma unroll 1
    for (int half = 0; half < 2; ++half) {
        const int node = half * 16 + ng;
        const int* ep = &eis[node * K_NBR];
#pragma unroll
        for (int q = 0; q < 2; ++q) {
            const int off = q * 32 + 2 * l16;     // u32 offset within row
            const uint2 sv = *(const uint2*)&xTb[(size_t)(nb + node) * 64 + off];
            float s0 = bflo(sv.x), s1 = bfhi(sv.x);
            float s2 = bflo(sv.y), s3 = bfhi(sv.y);
#pragma unroll
            for (int k = 0; k < K_NBR; ++k) {
                const uint2 v = *(const uint2*)&xTb[(size_t)ep[k] * 64 + off];
                s0 += bflo(v.x); s1 += bfhi(v.x);
                s2 += bflo(v.y); s3 += bfhi(v.y);
            }
            *(uint2*)&y[node][off] =
                make_uint2(pack_bf16x2(s0, s1), pack_bf16x2(s2, s3));
        }
    }
    __syncthreads();

    // ---- Phase 2: MFMA GEMM (K=256) — unchanged ----
    const int nh = wid & 1;
    const int oh = wid >> 1;
    const int arow = nh * 16 + (lane & 15);
    const int acol = (lane >> 4) * 4;

    bf16x8 afrag[8];
#pragma unroll
    for (int kb = 0; kb < 8; ++kb)
        afrag[kb] = *(const bf16x8*)&y[arow][kb * 16 + acol];

    f32x4 acc[4];
#pragma unroll
    for (int t = 0; t < 4; ++t) {
        f32x4 a = {0.f, 0.f, 0.f, 0.f};
#pragma unroll
        for (int kb = 0; kb < 8; ++kb) {
            bf16x8 bv = WB[((oh * 4 + t) * 8 + kb) * 64 + lane];
            a = __builtin_amdgcn_mfma_f32_16x16x32_bf16(afrag[kb], bv, a, 0, 0, 0);
        }
        acc[t] = a;
    }

    // ---- Phase 3: relu(acc + bias), store [C][N] — unchanged ----
    const int rbase = nh * 16 + (lane >> 4) * 4;
#pragma unroll
    for (int t = 0; t < 4; ++t) {
        const int o = oh * 64 + t * 16 + (lane & 15);
        const float bo = bias[o];
        float4 res;
        res.x = fmaxf(acc[t][0] + bo, 0.0f);
        res.y = fmaxf(acc[t][1] + bo, 0.0f);
        res.z = fmaxf(acc[t][2] + bo, 0.0f);
        res.w = fmaxf(acc[t][3] + bo, 0.0f);
        *(float4*)&out[(size_t)o * N_NODES + nb + rbase] = res;
    }
}

// ---------------------------------------------------------------------------
extern "C" void kernel_launch(void* const* d_in, const int* in_sizes, int n_in,
                              void* d_out, int out_size, void* d_ws, size_t ws_size,
                              hipStream_t stream) {
    const float* x    = (const float*)d_in[0];   // [1,128,40000,1]
    const float* x0   = (const float*)d_in[1];   // [1,40000,128]
    const int*   ei   = (const int*)  d_in[2];   // [2,1,40000,16]; row 0
    const float* W1   = (const float*)d_in[3];   // [128,128]
    const float* W2   = (const float*)d_in[4];   // [128,128]
    const float* bias = (const float*)d_in[5];   // [128]
    float* out = (float*)d_out;                  // [1,128,40000,1]

    // ws: [0, 64KB) WB' bf16 frags ; [64KB, 64KB+10.24MB) xTb
    unsigned short* WB  = (unsigned short*)d_ws;
    unsigned*       xTb = (unsigned*)((char*)d_ws + 65536);

    hipLaunchKernelGGL(prep_kernel, dim3(1378), dim3(256), 0, stream,
                       x, W1, W2, xTb, WB);
    hipLaunchKernelGGL(fused5_kernel, dim3(1250), dim3(256), 0, stream,
                       xTb, x0, ei, (const bf16x8*)WB, bias, out);
}

// Round 14
// 44.889 us; speedup vs baseline: 1.0040x; 1.0040x over previous
//
#include <hip/hip_runtime.h>

#define N_NODES 40000
#define C_DIM   128
#define K_NBR   16

static constexpr float BETA_F  = 0.11778303565638346f;  // log(1.125)
static constexpr float C1_F    = 0.7939952679092549f;   // (1-ALPHA)*(1-BETA)
static constexpr float C2_F    = 0.08822169643436166f;  // ALPHA*(1-BETA)
static constexpr float INV_DEG = 1.0f / 17.0f;

typedef __attribute__((ext_vector_type(8))) short bf16x8;
typedef __attribute__((ext_vector_type(4))) float f32x4;

__device__ __forceinline__ unsigned pack_bf16x2(float a, float b) {
    unsigned ua = __float_as_uint(a), ub = __float_as_uint(b);
    ua += 0x7fffu + ((ua >> 16) & 1u);     // RNE
    ub += 0x7fffu + ((ub >> 16) & 1u);
    return (ua >> 16) | (ub & 0xffff0000u);
}
__device__ __forceinline__ float bflo(unsigned u) { return __uint_as_float(u << 16); }
__device__ __forceinline__ float bfhi(unsigned u) { return __uint_as_float(u & 0xffff0000u); }

// ---------------------------------------------------------------------------
// Kernel 1 (prep) — identical to R7/R11 (best-known): grid = 128 + 1250.
//   blocks 0..127    : folded-W fragment build (parallel, 1 elem/thread).
//   blocks 128..1377 : transpose+cast 32n x 128c of x -> xTb [N][64] u32.
// W'[c][o] = c<128 ? (BETA*W1[o][c] + (c==o)*C1) * INV_DEG
//                  : BETA*W2[o][c-128] + (c-128==o)*C2
// ---------------------------------------------------------------------------
__global__ __launch_bounds__(256) void prep_kernel(
        const float* __restrict__ x,
        const float* __restrict__ W1,
        const float* __restrict__ W2,
        unsigned* __restrict__ xTb,
        unsigned short* __restrict__ WB) {
    __shared__ unsigned lds[32 * 65];   // [n][c2], stride 65 u32 (8320 B)

    const int b = blockIdx.x;
    const int tid = threadIdx.x;

    if (b < 128) {
        const int i = b * 256 + tid;                   // 0 .. 32767
        const int frag = i >> 9, within = i & 511;
        const int lane = within >> 3, j = within & 7;
        const int otile = frag >> 3, kblk = frag & 7;
        const int o = otile * 16 + (lane & 15);
        const int c = kblk * 32 + ((lane >> 4) << 3) + j;
        float v;
        if (c < 128) {
            v = (BETA_F * W1[o * 128 + c] + (c == o ? C1_F : 0.0f)) * INV_DEG;
        } else {
            const int c2 = c - 128;
            v = BETA_F * W2[o * 128 + c2] + (c2 == o ? C2_F : 0.0f);
        }
        unsigned u = __float_as_uint(v);
        u += 0x7fffu + ((u >> 16) & 1u);
        WB[i] = (unsigned short)(u >> 16);
        return;
    }

    const int nb = (b - 128) * 32;

    const int c2 = tid >> 2;          // 0..63
    const int h  = tid & 3;           // n-offset h*8
    const float* r0 = &x[(size_t)(2 * c2)     * N_NODES + nb + h * 8];
    const float* r1 = &x[(size_t)(2 * c2 + 1) * N_NODES + nb + h * 8];
    const float4 a0 = *(const float4*)(r0);
    const float4 a1 = *(const float4*)(r0 + 4);
    const float4 b0 = *(const float4*)(r1);
    const float4 b1 = *(const float4*)(r1 + 4);

    unsigned* lrow = &lds[h * 8 * 65 + c2];
    lrow[0 * 65] = pack_bf16x2(a0.x, b0.x);
    lrow[1 * 65] = pack_bf16x2(a0.y, b0.y);
    lrow[2 * 65] = pack_bf16x2(a0.z, b0.z);
    lrow[3 * 65] = pack_bf16x2(a0.w, b0.w);
    lrow[4 * 65] = pack_bf16x2(a1.x, b1.x);
    lrow[5 * 65] = pack_bf16x2(a1.y, b1.y);
    lrow[6 * 65] = pack_bf16x2(a1.z, b1.z);
    lrow[7 * 65] = pack_bf16x2(a1.w, b1.w);
    __syncthreads();

    const int n = tid >> 3, q = tid & 7;
    const unsigned* src = &lds[n * 65 + q * 8];
    unsigned* dst = &xTb[(size_t)(nb + n) * 64 + q * 8];
    *(uint4*)&dst[0] = make_uint4(src[0], src[1], src[2], src[3]);
    *(uint4*)&dst[4] = make_uint4(src[4], src[5], src[6], src[7]);
}

// ---------------------------------------------------------------------------
// Kernel 2 (fused): gather-sum — R11 organization (8 lanes/node, 32 nodes,
// reg-hoisted indices) but uint4 loads in 2 half-row passes: half the load
// instructions, full 128-B line per (node,k) transaction.
// Block = 256 threads (4 waves), 32 nodes/block, grid = 1250.
// ---------------------------------------------------------------------------
__global__ __launch_bounds__(256) void fused6_kernel(
        const unsigned* __restrict__ xTb,     // [N][64] u32 = bf16x2
        const float*    __restrict__ x0,      // [N][128] f32
        const int*      __restrict__ e0,      // [N][16]
        const bf16x8*   __restrict__ WB,      // 64 frags x 64 lanes x 16B
        const float*    __restrict__ bias,    // [128]
        float*          __restrict__ out) {   // [128][N]
    __shared__ unsigned y[32][132];           // [node][sum(64) | x0(64) | pad 4]
    __shared__ int eis[512];

    const int nb   = blockIdx.x * 32;
    const int tid  = threadIdx.x;
    const int lane = tid & 63;
    const int wid  = tid >> 6;

    eis[tid]       = e0[(size_t)nb * K_NBR + tid];
    eis[256 + tid] = e0[(size_t)nb * K_NBR + 256 + tid];
    __syncthreads();

    // ---- Phase 1a: stage x0 tile (bf16) — issued early, independent ----
    const int node = tid >> 3;        // 0..31
    const int g8   = tid & 7;         // 0..7
    {
        const float* r = &x0[(size_t)(nb + node) * C_DIM + g8 * 16];
        const float4 v0 = *(const float4*)(r);
        const float4 v1 = *(const float4*)(r + 4);
        const float4 v2 = *(const float4*)(r + 8);
        const float4 v3 = *(const float4*)(r + 12);
        uint4 ua, ub;
        ua.x = pack_bf16x2(v0.x, v0.y);  ua.y = pack_bf16x2(v0.z, v0.w);
        ua.z = pack_bf16x2(v1.x, v1.y);  ua.w = pack_bf16x2(v1.z, v1.w);
        ub.x = pack_bf16x2(v2.x, v2.y);  ub.y = pack_bf16x2(v2.z, v2.w);
        ub.z = pack_bf16x2(v3.x, v3.y);  ub.w = pack_bf16x2(v3.z, v3.w);
        *(uint4*)&y[node][64 + g8 * 8]     = ua;
        *(uint4*)&y[node][64 + g8 * 8 + 4] = ub;
    }

    // ---- Phase 1b: neighbor indices -> registers (statically indexed) ----
    int jreg[K_NBR];
#pragma unroll
    for (int k = 0; k < K_NBR; ++k) jreg[k] = eis[node * K_NBR + k];

    // ---- Phase 1c: gather-sum, 2 half-row passes, uint4 per lane ----
#pragma unroll 1
    for (int q = 0; q < 2; ++q) {
        const int off = q * 32 + 4 * g8;          // u32 offset within row
        const uint4 sv = *(const uint4*)&xTb[(size_t)(nb + node) * 64 + off];
        float s0 = bflo(sv.x), s1 = bfhi(sv.x);
        float s2 = bflo(sv.y), s3 = bfhi(sv.y);
        float s4 = bflo(sv.z), s5 = bfhi(sv.z);
        float s6 = bflo(sv.w), s7 = bfhi(sv.w);
#pragma unroll
        for (int k = 0; k < K_NBR; ++k) {
            const uint4 v = *(const uint4*)&xTb[(size_t)jreg[k] * 64 + off];
            s0 += bflo(v.x); s1 += bfhi(v.x);
            s2 += bflo(v.y); s3 += bfhi(v.y);
            s4 += bflo(v.z); s5 += bfhi(v.z);
            s6 += bflo(v.w); s7 += bfhi(v.w);
        }
        uint4 pv;
        pv.x = pack_bf16x2(s0, s1);
        pv.y = pack_bf16x2(s2, s3);
        pv.z = pack_bf16x2(s4, s5);
        pv.w = pack_bf16x2(s6, s7);
        *(uint4*)&y[node][off] = pv;
    }
    __syncthreads();

    // ---- Phase 2: MFMA GEMM (K=256) — unchanged from R11 ----
    const int nh = wid & 1;
    const int oh = wid >> 1;
    const int arow = nh * 16 + (lane & 15);
    const int acol = (lane >> 4) * 4;

    bf16x8 afrag[8];
#pragma unroll
    for (int kb = 0; kb < 8; ++kb)
        afrag[kb] = *(const bf16x8*)&y[arow][kb * 16 + acol];

    f32x4 acc[4];
#pragma unroll
    for (int t = 0; t < 4; ++t) {
        f32x4 a = {0.f, 0.f, 0.f, 0.f};
#pragma unroll
        for (int kb = 0; kb < 8; ++kb) {
            bf16x8 bv = WB[((oh * 4 + t) * 8 + kb) * 64 + lane];
            a = __builtin_amdgcn_mfma_f32_16x16x32_bf16(afrag[kb], bv, a, 0, 0, 0);
        }
        acc[t] = a;
    }

    // ---- Phase 3: relu(acc + bias), store [C][N] — unchanged ----
    const int rbase = nh * 16 + (lane >> 4) * 4;
#pragma unroll
    for (int t = 0; t < 4; ++t) {
        const int o = oh * 64 + t * 16 + (lane & 15);
        const float bo = bias[o];
        float4 res;
        res.x = fmaxf(acc[t][0] + bo, 0.0f);
        res.y = fmaxf(acc[t][1] + bo, 0.0f);
        res.z = fmaxf(acc[t][2] + bo, 0.0f);
        res.w = fmaxf(acc[t][3] + bo, 0.0f);
        *(float4*)&out[(size_t)o * N_NODES + nb + rbase] = res;
    }
}

// ---------------------------------------------------------------------------
extern "C" void kernel_launch(void* const* d_in, const int* in_sizes, int n_in,
                              void* d_out, int out_size, void* d_ws, size_t ws_size,
                              hipStream_t stream) {
    const float* x    = (const float*)d_in[0];   // [1,128,40000,1]
    const float* x0   = (const float*)d_in[1];   // [1,40000,128]
    const int*   ei   = (const int*)  d_in[2];   // [2,1,40000,16]; row 0
    const float* W1   = (const float*)d_in[3];   // [128,128]
    const float* W2   = (const float*)d_in[4];   // [128,128]
    const float* bias = (const float*)d_in[5];   // [128]
    float* out = (float*)d_out;                  // [1,128,40000,1]

    // ws: [0, 64KB) WB' bf16 frags ; [64KB, 64KB+10.24MB) xTb
    unsigned short* WB  = (unsigned short*)d_ws;
    unsigned*       xTb = (unsigned*)((char*)d_ws + 65536);

    hipLaunchKernelGGL(prep_kernel, dim3(1378), dim3(256), 0, stream,
                       x, W1, W2, xTb, WB);
    hipLaunchKernelGGL(fused6_kernel, dim3(1250), dim3(256), 0, stream,
                       xTb, x0, ei, (const bf16x8*)WB, bias, out);
}

// Round 15
// 42.190 us; speedup vs baseline: 1.0683x; 1.0640x over previous
//
#include <hip/hip_runtime.h>

#define N_NODES 40000
#define C_DIM   128
#define K_NBR   16

static constexpr float BETA_F  = 0.11778303565638346f;  // log(1.125)
static constexpr float C1_F    = 0.7939952679092549f;   // (1-ALPHA)*(1-BETA)
static constexpr float C2_F    = 0.08822169643436166f;  // ALPHA*(1-BETA)
static constexpr float INV_DEG = 1.0f / 17.0f;

typedef __attribute__((ext_vector_type(8))) short bf16x8;
typedef __attribute__((ext_vector_type(4))) float f32x4;

__device__ __forceinline__ unsigned pack_bf16x2(float a, float b) {
    unsigned ua = __float_as_uint(a), ub = __float_as_uint(b);
    ua += 0x7fffu + ((ua >> 16) & 1u);     // RNE
    ub += 0x7fffu + ((ub >> 16) & 1u);
    return (ua >> 16) | (ub & 0xffff0000u);
}
__device__ __forceinline__ float bflo(unsigned u) { return __uint_as_float(u << 16); }
__device__ __forceinline__ float bfhi(unsigned u) { return __uint_as_float(u & 0xffff0000u); }

// ---------------------------------------------------------------------------
// Kernel 1 (prep) — identical to R7/R11 (best-known): grid = 128 + 1250.
//   blocks 0..127    : folded-W fragment build (parallel, 1 elem/thread).
//   blocks 128..1377 : transpose+cast 32n x 128c of x -> xTb [N][64] u32.
// W'[c][o] = c<128 ? (BETA*W1[o][c] + (c==o)*C1) * INV_DEG
//                  : BETA*W2[o][c-128] + (c-128==o)*C2
// ---------------------------------------------------------------------------
__global__ __launch_bounds__(256) void prep_kernel(
        const float* __restrict__ x,
        const float* __restrict__ W1,
        const float* __restrict__ W2,
        unsigned* __restrict__ xTb,
        unsigned short* __restrict__ WB) {
    __shared__ unsigned lds[32 * 65];   // [n][c2], stride 65 u32 (8320 B)

    const int b = blockIdx.x;
    const int tid = threadIdx.x;

    if (b < 128) {
        const int i = b * 256 + tid;                   // 0 .. 32767
        const int frag = i >> 9, within = i & 511;
        const int lane = within >> 3, j = within & 7;
        const int otile = frag >> 3, kblk = frag & 7;
        const int o = otile * 16 + (lane & 15);
        const int c = kblk * 32 + ((lane >> 4) << 3) + j;
        float v;
        if (c < 128) {
            v = (BETA_F * W1[o * 128 + c] + (c == o ? C1_F : 0.0f)) * INV_DEG;
        } else {
            const int c2 = c - 128;
            v = BETA_F * W2[o * 128 + c2] + (c2 == o ? C2_F : 0.0f);
        }
        unsigned u = __float_as_uint(v);
        u += 0x7fffu + ((u >> 16) & 1u);
        WB[i] = (unsigned short)(u >> 16);
        return;
    }

    const int nb = (b - 128) * 32;

    const int c2 = tid >> 2;          // 0..63
    const int h  = tid & 3;           // n-offset h*8
    const float* r0 = &x[(size_t)(2 * c2)     * N_NODES + nb + h * 8];
    const float* r1 = &x[(size_t)(2 * c2 + 1) * N_NODES + nb + h * 8];
    const float4 a0 = *(const float4*)(r0);
    const float4 a1 = *(const float4*)(r0 + 4);
    const float4 b0 = *(const float4*)(r1);
    const float4 b1 = *(const float4*)(r1 + 4);

    unsigned* lrow = &lds[h * 8 * 65 + c2];
    lrow[0 * 65] = pack_bf16x2(a0.x, b0.x);
    lrow[1 * 65] = pack_bf16x2(a0.y, b0.y);
    lrow[2 * 65] = pack_bf16x2(a0.z, b0.z);
    lrow[3 * 65] = pack_bf16x2(a0.w, b0.w);
    lrow[4 * 65] = pack_bf16x2(a1.x, b1.x);
    lrow[5 * 65] = pack_bf16x2(a1.y, b1.y);
    lrow[6 * 65] = pack_bf16x2(a1.z, b1.z);
    lrow[7 * 65] = pack_bf16x2(a1.w, b1.w);
    __syncthreads();

    const int n = tid >> 3, q = tid & 7;
    const unsigned* src = &lds[n * 65 + q * 8];
    unsigned* dst = &xTb[(size_t)(nb + n) * 64 + q * 8];
    *(uint4*)&dst[0] = make_uint4(src[0], src[1], src[2], src[3]);
    *(uint4*)&dst[4] = make_uint4(src[4], src[5], src[6], src[7]);
}

// ---------------------------------------------------------------------------
// Kernel 2 (fused): 16 nodes/block, 2500 blocks -> 8 blocks/CU resident
// (32 waves/CU, 1.6x R11's 20) for gather latency hiding; tail halves.
// Gather: 16 lanes/node, uint2, 2 half-row passes (same 8.5 instr/node and
// L2-hit re-touch economics as R11's proven best).
// Pairing swizzle: tiles 2t,2t+1 -> block indices congruent mod 8 (same XCD
// under round-robin dispatch) so the two 64-B halves of each out line merge.
// ---------------------------------------------------------------------------
__global__ __launch_bounds__(256) void fused7_kernel(
        const unsigned* __restrict__ xTb,     // [N][64] u32 = bf16x2
        const float*    __restrict__ x0,      // [N][128] f32
        const int*      __restrict__ e0,      // [N][16]
        const bf16x8*   __restrict__ WB,      // 64 frags x 64 lanes x 16B
        const float*    __restrict__ bias,    // [128]
        float*          __restrict__ out) {   // [128][N]
    __shared__ unsigned y[16][132];           // [node][sum(64) | x0(64) | pad 4]
    __shared__ int eis[256];

    // ---- tile index with XCD-pairing swizzle ----
    const int b = blockIdx.x;
    int tile;
    if (b >= 2496) {
        tile = b;
    } else {
        const int g = b >> 4, w = b & 15;
        tile = g * 16 + (w & 7) * 2 + (w >> 3);
    }
    const int nb  = tile * 16;
    const int tid = threadIdx.x;
    const int lane = tid & 63;
    const int wid  = tid >> 6;

    eis[tid] = e0[(size_t)nb * K_NBR + tid];   // 16 nodes x 16 = 256
    __syncthreads();

    const int node = tid >> 4;        // 0..15
    const int g16  = tid & 15;        // 0..15

    // ---- Phase 1a: stage x0 tile (bf16) ----
    {
        const float* r = &x0[(size_t)(nb + node) * C_DIM + g16 * 8];
        const float4 v0 = *(const float4*)(r);
        const float4 v1 = *(const float4*)(r + 4);
        uint4 ua;
        ua.x = pack_bf16x2(v0.x, v0.y);  ua.y = pack_bf16x2(v0.z, v0.w);
        ua.z = pack_bf16x2(v1.x, v1.y);  ua.w = pack_bf16x2(v1.z, v1.w);
        *(uint4*)&y[node][64 + g16 * 4] = ua;
    }

    // ---- Phase 1b: neighbor indices -> registers (statically indexed) ----
    int jreg[K_NBR];
#pragma unroll
    for (int k = 0; k < K_NBR; ++k) jreg[k] = eis[node * K_NBR + k];

    // ---- Phase 1c: gather-sum, 2 half-row passes, uint2 per lane ----
#pragma unroll 1
    for (int q = 0; q < 2; ++q) {
        const int off = q * 32 + 2 * g16;         // u32 offset within row
        const uint2 sv = *(const uint2*)&xTb[(size_t)(nb + node) * 64 + off];
        float s0 = bflo(sv.x), s1 = bfhi(sv.x);
        float s2 = bflo(sv.y), s3 = bfhi(sv.y);
#pragma unroll
        for (int k = 0; k < K_NBR; ++k) {
            const uint2 v = *(const uint2*)&xTb[(size_t)jreg[k] * 64 + off];
            s0 += bflo(v.x); s1 += bfhi(v.x);
            s2 += bflo(v.y); s3 += bfhi(v.y);
        }
        *(uint2*)&y[node][off] =
            make_uint2(pack_bf16x2(s0, s1), pack_bf16x2(s2, s3));
    }
    __syncthreads();

    // ---- Phase 2: MFMA GEMM (16 rows, K=256); wave wid -> o 32-block ----
    const int arow = lane & 15;
    const int acol = (lane >> 4) * 4;

    bf16x8 afrag[8];
#pragma unroll
    for (int kb = 0; kb < 8; ++kb)
        afrag[kb] = *(const bf16x8*)&y[arow][kb * 16 + acol];

    f32x4 acc[2];
#pragma unroll
    for (int t = 0; t < 2; ++t) {
        f32x4 a = {0.f, 0.f, 0.f, 0.f};
        const int otile = wid * 2 + t;
#pragma unroll
        for (int kb = 0; kb < 8; ++kb) {
            bf16x8 bv = WB[(otile * 8 + kb) * 64 + lane];
            a = __builtin_amdgcn_mfma_f32_16x16x32_bf16(afrag[kb], bv, a, 0, 0, 0);
        }
        acc[t] = a;
    }

    // ---- Phase 3: relu(acc + bias), store [C][N] (64-B runs) ----
    const int rbase = (lane >> 4) * 4;
#pragma unroll
    for (int t = 0; t < 2; ++t) {
        const int o = wid * 32 + t * 16 + (lane & 15);
        const float bo = bias[o];
        float4 res;
        res.x = fmaxf(acc[t][0] + bo, 0.0f);
        res.y = fmaxf(acc[t][1] + bo, 0.0f);
        res.z = fmaxf(acc[t][2] + bo, 0.0f);
        res.w = fmaxf(acc[t][3] + bo, 0.0f);
        *(float4*)&out[(size_t)o * N_NODES + nb + rbase] = res;
    }
}

// ---------------------------------------------------------------------------
extern "C" void kernel_launch(void* const* d_in, const int* in_sizes, int n_in,
                              void* d_out, int out_size, void* d_ws, size_t ws_size,
                              hipStream_t stream) {
    const float* x    = (const float*)d_in[0];   // [1,128,40000,1]
    const float* x0   = (const float*)d_in[1];   // [1,40000,128]
    const int*   ei   = (const int*)  d_in[2];   // [2,1,40000,16]; row 0
    const float* W1   = (const float*)d_in[3];   // [128,128]
    const float* W2   = (const float*)d_in[4];   // [128,128]
    const float* bias = (const float*)d_in[5];   // [128]
    float* out = (float*)d_out;                  // [1,128,40000,1]

    // ws: [0, 64KB) WB' bf16 frags ; [64KB, 64KB+10.24MB) xTb
    unsigned short* WB  = (unsigned short*)d_ws;
    unsigned*       xTb = (unsigned*)((char*)d_ws + 65536);

    hipLaunchKernelGGL(prep_kernel, dim3(1378), dim3(256), 0, stream,
                       x, W1, W2, xTb, WB);
    hipLaunchKernelGGL(fused7_kernel, dim3(2500), dim3(256), 0, stream,
                       xTb, x0, ei, (const bf16x8*)WB, bias, out);
}

// Round 16
// 41.806 us; speedup vs baseline: 1.0781x; 1.0092x over previous
//
#include <hip/hip_runtime.h>

#define N_NODES 40000
#define C_DIM   128
#define K_NBR   16

static constexpr float BETA_F  = 0.11778303565638346f;  // log(1.125)
static constexpr float C1_F    = 0.7939952679092549f;   // (1-ALPHA)*(1-BETA)
static constexpr float C2_F    = 0.08822169643436166f;  // ALPHA*(1-BETA)
static constexpr float INV_DEG = 1.0f / 17.0f;

typedef __attribute__((ext_vector_type(8))) short bf16x8;
typedef __attribute__((ext_vector_type(4))) float f32x4;
typedef __attribute__((ext_vector_type(2))) float f32x2;

__device__ __forceinline__ unsigned pack_bf16x2(float a, float b) {
    unsigned ua = __float_as_uint(a), ub = __float_as_uint(b);
    ua += 0x7fffu + ((ua >> 16) & 1u);     // RNE
    ub += 0x7fffu + ((ub >> 16) & 1u);
    return (ua >> 16) | (ub & 0xffff0000u);
}

// ---------------------------------------------------------------------------
// Kernel 1 (prep): grid = 128 + 1250.
//   blocks 0..127    : folded-W bf16 fragment build (unchanged — GEMM stays bf16).
//   blocks 128..1377 : transpose 32n x 128c of x -> xT8 [N][32] u32 of fp8
//                      e4m3 (HW v_cvt_pk_fp8_f32).  Row = 128 B = ONE L2 line.
// W'[c][o] = c<128 ? (BETA*W1[o][c] + (c==o)*C1) * INV_DEG
//                  : BETA*W2[o][c-128] + (c-128==o)*C2
// ---------------------------------------------------------------------------
__global__ __launch_bounds__(256) void prep_kernel(
        const float* __restrict__ x,
        const float* __restrict__ W1,
        const float* __restrict__ W2,
        unsigned* __restrict__ xT8,
        unsigned short* __restrict__ WB) {
    __shared__ unsigned lds8[32 * 33];  // [n][c4], stride 33 u32 (4224 B)

    const int b = blockIdx.x;
    const int tid = threadIdx.x;

    if (b < 128) {
        const int i = b * 256 + tid;                   // 0 .. 32767
        const int frag = i >> 9, within = i & 511;
        const int lane = within >> 3, j = within & 7;
        const int otile = frag >> 3, kblk = frag & 7;
        const int o = otile * 16 + (lane & 15);
        const int c = kblk * 32 + ((lane >> 4) << 3) + j;
        float v;
        if (c < 128) {
            v = (BETA_F * W1[o * 128 + c] + (c == o ? C1_F : 0.0f)) * INV_DEG;
        } else {
            const int c2 = c - 128;
            v = BETA_F * W2[o * 128 + c2] + (c2 == o ? C2_F : 0.0f);
        }
        unsigned u = __float_as_uint(v);
        u += 0x7fffu + ((u >> 16) & 1u);
        WB[i] = (unsigned short)(u >> 16);
        return;
    }

    const int nb = (b - 128) * 32;

    // ---- load 4 channel rows x 4 nodes, encode fp8, stage [n][c4] ----
    const int c4 = tid >> 3;          // 0..31 -> channels 4c4..4c4+3
    const int h  = tid & 7;           // nodes nb+4h..+3
    const float4 v0 = *(const float4*)&x[(size_t)(4 * c4 + 0) * N_NODES + nb + 4 * h];
    const float4 v1 = *(const float4*)&x[(size_t)(4 * c4 + 1) * N_NODES + nb + 4 * h];
    const float4 v2 = *(const float4*)&x[(size_t)(4 * c4 + 2) * N_NODES + nb + 4 * h];
    const float4 v3 = *(const float4*)&x[(size_t)(4 * c4 + 3) * N_NODES + nb + 4 * h];
    {
        unsigned u;
        u = __builtin_amdgcn_cvt_pk_fp8_f32(v0.x, v1.x, 0u, false);
        u = __builtin_amdgcn_cvt_pk_fp8_f32(v2.x, v3.x, u, true);
        lds8[(4 * h + 0) * 33 + c4] = u;
        u = __builtin_amdgcn_cvt_pk_fp8_f32(v0.y, v1.y, 0u, false);
        u = __builtin_amdgcn_cvt_pk_fp8_f32(v2.y, v3.y, u, true);
        lds8[(4 * h + 1) * 33 + c4] = u;
        u = __builtin_amdgcn_cvt_pk_fp8_f32(v0.z, v1.z, 0u, false);
        u = __builtin_amdgcn_cvt_pk_fp8_f32(v2.z, v3.z, u, true);
        lds8[(4 * h + 2) * 33 + c4] = u;
        u = __builtin_amdgcn_cvt_pk_fp8_f32(v0.w, v1.w, 0u, false);
        u = __builtin_amdgcn_cvt_pk_fp8_f32(v2.w, v3.w, u, true);
        lds8[(4 * h + 3) * 33 + c4] = u;
    }
    __syncthreads();

    // ---- write: (n = tid>>3, q = tid&7) -> 16 B; 8 lanes = full 128-B row ----
    const int n = tid >> 3, q = tid & 7;
    const unsigned* src = &lds8[n * 33 + q * 4];
    *(uint4*)&xT8[(size_t)(nb + n) * 32 + q * 4] =
        make_uint4(src[0], src[1], src[2], src[3]);
}

// ---------------------------------------------------------------------------
// Kernel 2 (fused): fp8 gather-sum (R11 organization: 8 lanes/node, reg-
// hoisted indices, 2 half-row passes) + bf16 MFMA GEMM + relu/bias epilogue.
// Block = 256 threads (4 waves), 32 nodes/block, grid = 1250.
// ---------------------------------------------------------------------------
__global__ __launch_bounds__(256) void fused8_kernel(
        const unsigned* __restrict__ xT8,     // [N][32] u32 = 4x fp8 e4m3
        const float*    __restrict__ x0,      // [N][128] f32
        const int*      __restrict__ e0,      // [N][16]
        const bf16x8*   __restrict__ WB,      // 64 frags x 64 lanes x 16B
        const float*    __restrict__ bias,    // [128]
        float*          __restrict__ out) {   // [128][N]
    __shared__ unsigned y[32][132];           // [node][sum(64) | x0(64) | pad 4]
    __shared__ int eis[512];

    const int nb   = blockIdx.x * 32;
    const int tid  = threadIdx.x;
    const int lane = tid & 63;
    const int wid  = tid >> 6;

    eis[tid]       = e0[(size_t)nb * K_NBR + tid];
    eis[256 + tid] = e0[(size_t)nb * K_NBR + 256 + tid];
    __syncthreads();

    const int node = tid >> 3;        // 0..31
    const int g8   = tid & 7;         // 0..7

    // ---- Phase 1a: stage x0 tile (bf16) — issued early, independent ----
    {
        const float* r = &x0[(size_t)(nb + node) * C_DIM + g8 * 16];
        const float4 v0 = *(const float4*)(r);
        const float4 v1 = *(const float4*)(r + 4);
        const float4 v2 = *(const float4*)(r + 8);
        const float4 v3 = *(const float4*)(r + 12);
        uint4 ua, ub;
        ua.x = pack_bf16x2(v0.x, v0.y);  ua.y = pack_bf16x2(v0.z, v0.w);
        ua.z = pack_bf16x2(v1.x, v1.y);  ua.w = pack_bf16x2(v1.z, v1.w);
        ub.x = pack_bf16x2(v2.x, v2.y);  ub.y = pack_bf16x2(v2.z, v2.w);
        ub.z = pack_bf16x2(v3.x, v3.y);  ub.w = pack_bf16x2(v3.z, v3.w);
        *(uint4*)&y[node][64 + g8 * 8]     = ua;
        *(uint4*)&y[node][64 + g8 * 8 + 4] = ub;
    }

    // ---- Phase 1b: neighbor indices -> registers (statically indexed) ----
    int jreg[K_NBR];
#pragma unroll
    for (int k = 0; k < K_NBR; ++k) jreg[k] = eis[node * K_NBR + k];

    // ---- Phase 1c: fp8 gather-sum, 2 half-row passes, uint2 per lane ----
#pragma unroll 1
    for (int q = 0; q < 2; ++q) {
        const int off = q * 16 + 2 * g8;          // u32 offset within 32-u32 row
        float s0, s1, s2, s3, s4, s5, s6, s7;
        {
            const uint2 sv = *(const uint2*)&xT8[(size_t)(nb + node) * 32 + off];
            const f32x2 p0 = __builtin_amdgcn_cvt_pk_f32_fp8(sv.x, false);
            const f32x2 p1 = __builtin_amdgcn_cvt_pk_f32_fp8(sv.x, true);
            const f32x2 p2 = __builtin_amdgcn_cvt_pk_f32_fp8(sv.y, false);
            const f32x2 p3 = __builtin_amdgcn_cvt_pk_f32_fp8(sv.y, true);
            s0 = p0[0]; s1 = p0[1]; s2 = p1[0]; s3 = p1[1];
            s4 = p2[0]; s5 = p2[1]; s6 = p3[0]; s7 = p3[1];
        }
#pragma unroll
        for (int k = 0; k < K_NBR; ++k) {
            const uint2 v = *(const uint2*)&xT8[(size_t)jreg[k] * 32 + off];
            const f32x2 p0 = __builtin_amdgcn_cvt_pk_f32_fp8(v.x, false);
            const f32x2 p1 = __builtin_amdgcn_cvt_pk_f32_fp8(v.x, true);
            const f32x2 p2 = __builtin_amdgcn_cvt_pk_f32_fp8(v.y, false);
            const f32x2 p3 = __builtin_amdgcn_cvt_pk_f32_fp8(v.y, true);
            s0 += p0[0]; s1 += p0[1]; s2 += p1[0]; s3 += p1[1];
            s4 += p2[0]; s5 += p2[1]; s6 += p3[0]; s7 += p3[1];
        }
        // channels [q*64 + g8*8, +8) -> y cols [q*32 + g8*4, +4)
        uint4 pv;
        pv.x = pack_bf16x2(s0, s1);
        pv.y = pack_bf16x2(s2, s3);
        pv.z = pack_bf16x2(s4, s5);
        pv.w = pack_bf16x2(s6, s7);
        *(uint4*)&y[node][q * 32 + g8 * 4] = pv;
    }
    __syncthreads();

    // ---- Phase 2: MFMA GEMM (K=256) — unchanged from R11 ----
    const int nh = wid & 1;
    const int oh = wid >> 1;
    const int arow = nh * 16 + (lane & 15);
    const int acol = (lane >> 4) * 4;

    bf16x8 afrag[8];
#pragma unroll
    for (int kb = 0; kb < 8; ++kb)
        afrag[kb] = *(const bf16x8*)&y[arow][kb * 16 + acol];

    f32x4 acc[4];
#pragma unroll
    for (int t = 0; t < 4; ++t) {
        f32x4 a = {0.f, 0.f, 0.f, 0.f};
#pragma unroll
        for (int kb = 0; kb < 8; ++kb) {
            bf16x8 bv = WB[((oh * 4 + t) * 8 + kb) * 64 + lane];
            a = __builtin_amdgcn_mfma_f32_16x16x32_bf16(afrag[kb], bv, a, 0, 0, 0);
        }
        acc[t] = a;
    }

    // ---- Phase 3: relu(acc + bias), store [C][N] — unchanged ----
    const int rbase = nh * 16 + (lane >> 4) * 4;
#pragma unroll
    for (int t = 0; t < 4; ++t) {
        const int o = oh * 64 + t * 16 + (lane & 15);
        const float bo = bias[o];
        float4 res;
        res.x = fmaxf(acc[t][0] + bo, 0.0f);
        res.y = fmaxf(acc[t][1] + bo, 0.0f);
        res.z = fmaxf(acc[t][2] + bo, 0.0f);
        res.w = fmaxf(acc[t][3] + bo, 0.0f);
        *(float4*)&out[(size_t)o * N_NODES + nb + rbase] = res;
    }
}

// ---------------------------------------------------------------------------
extern "C" void kernel_launch(void* const* d_in, const int* in_sizes, int n_in,
                              void* d_out, int out_size, void* d_ws, size_t ws_size,
                              hipStream_t stream) {
    const float* x    = (const float*)d_in[0];   // [1,128,40000,1]
    const float* x0   = (const float*)d_in[1];   // [1,40000,128]
    const int*   ei   = (const int*)  d_in[2];   // [2,1,40000,16]; row 0
    const float* W1   = (const float*)d_in[3];   // [128,128]
    const float* W2   = (const float*)d_in[4];   // [128,128]
    const float* bias = (const float*)d_in[5];   // [128]
    float* out = (float*)d_out;                  // [1,128,40000,1]

    // ws: [0, 64KB) WB' bf16 frags ; [64KB, 64KB+5.12MB) xT8 (fp8)
    unsigned short* WB  = (unsigned short*)d_ws;
    unsigned*       xT8 = (unsigned*)((char*)d_ws + 65536);

    hipLaunchKernelGGL(prep_kernel, dim3(1378), dim3(256), 0, stream,
                       x, W1, W2, xT8, WB);
    hipLaunchKernelGGL(fused8_kernel, dim3(1250), dim3(256), 0, stream,
                       xT8, x0, ei, (const bf16x8*)WB, bias, out);
}